// Round 9
// baseline (405.044 us; speedup 1.0000x reference)
//
#include <hip/hip_runtime.h>
#include <math.h>

// RoutingLayer fused via split-fp16 MFMA emulation of fp32 GEMM.
// routing = x@w_gate + noise*(softplus(x@w_noise)+0.01); out = scatter(softmax(top2)).
// x: 32768x2048 fp32, w_*: 2048x64 fp32, noise: 32768x64, out: 32768x64.
//
// R12: staging-instruction minimization. Fitting R4-R11 + m97: perf tracks
// the count of global_load_lds / scattered-VMEM instructions per block-chunk
// at ~100-130 cy EACH of a serialized per-CU resource -- barriers, pipeline
// depth, occupancy games were all null because they never changed that count.
// Fix: amortize B-staging over 2x rows. BM=128, 1024-thr blocks (16 waves =
// 4 row-groups x 4 col-tiles), grid 256 = 1 block/CU (16 waves/CU kept).
// Per block-chunk: 16 B-DMA + 16 x-DMA = 32 instrs for 128 rows (0.25/row)
// vs R11's 48/64 rows (0.375/row). Everything else is R11's verified code:
// XOR-swizzled x source (rule #21 pair), in-register split-fp16 convert,
// 32x32x16 MFMA, one barrier/chunk, DMA issued a full chunk ahead.

typedef _Float16 half8v __attribute__((ext_vector_type(8)));
typedef float f32x16 __attribute__((ext_vector_type(16)));

constexpr int DIMK = 2048;
constexpr int NEXP = 64;
constexpr int BM   = 128;        // rows per block
constexpr int NCH  = DIMK / 32;  // 64 k-chunks of 32

__device__ __forceinline__ void async_load16(const void* g, void* l) {
    // global -> LDS DMA, 16B/lane; LDS dest = uniform base + lane*16,
    // GLOBAL source is per-lane (enables source-side swizzling, m173).
    __builtin_amdgcn_global_load_lds(
        (const __attribute__((address_space(1))) unsigned int*)g,
        (__attribute__((address_space(3))) unsigned int*)l, 16, 0, 0);
}

__device__ __forceinline__ bool gt_pair(float a, int ia, float b, int ib) {
    return (a > b) || (a == b && ia < ib);   // jax top_k: lower index wins ties
}

// ---- pre-kernel: split w' = 65536*[wg|wn] into 2 fp16 planes in 32x32x16
// B-frag order. Frag-block fb = c*16 + kh*8 + p*4 + nt  (1KB each, 1MB total):
// lane holds B[k = c*32 + kh*16 + (lane>>5)*8 + j][n' = nt*32 + (lane&31)]
// where nt 0,1 = w_gate cols 0..63 and nt 2,3 = w_noise cols 0..63.
__global__ __launch_bounds__(256)
void presplit_kernel(const float* __restrict__ wg, const float* __restrict__ wn,
                     _Float16* __restrict__ wsB)
{
    int gid  = blockIdx.x * 256 + threadIdx.x;   // 0..65535 = (fb, lane)
    int lane = gid & 63;
    int fb   = gid >> 6;          // 0..1023
    int nt   = fb & 3;
    int p    = (fb >> 2) & 1;
    int kh   = (fb >> 3) & 1;
    int c    = fb >> 4;
    const float* src = (nt < 2) ? (wg + nt * 32 + (lane & 31))
                                : (wn + (nt - 2) * 32 + (lane & 31));
    int kb = c * 32 + kh * 16 + ((lane >> 5) << 3);
    half8v hp;
    #pragma unroll
    for (int j = 0; j < 8; ++j) {
        float w = src[(size_t)(kb + j) * NEXP] * 65536.0f;
        _Float16 a = (_Float16)w;
        hp[j] = p ? (_Float16)(w - (float)a) : a;
    }
    *(half8v*)(wsB + (size_t)fb * 512 + lane * 8) = hp;
}

// ---- main kernel: 1024 threads = 16 waves as (rg = w>>2, t = w&3).
// Wave tile: 32 rows (rg) x 32 cols of tile t (0=gate-lo,1=gate-hi,2=noise-lo,3=noise-hi).
__global__ __launch_bounds__(1024, 4)
void routing_mfma(const float* __restrict__ x, const _Float16* __restrict__ wsB,
                  const float* __restrict__ noise, float* __restrict__ out)
{
    // 69 KB: [Bs: 2 x 16KB][Xs: 2 x 16KB]; whole region reused as epilogue scratch.
    __shared__ __align__(16) char smem[70656];
    _Float16* Bs = (_Float16*)smem;              // [2][8192] halfs
    float*    Xs = (float*)(smem + 32768);       // [2][4096] floats

    const int tid  = threadIdx.x;
    const int lane = tid & 63;
    const int w    = tid >> 6;          // 0..15
    const int rg   = w >> 2;            // row group (0..3)
    const int t    = w & 3;             // col tile
    const int m    = lane & 31;
    const int h    = lane >> 5;
    const int row0 = blockIdx.x * BM;

    f32x16 acc = {};

    // ---- staging: 2 DMA instrs per wave per chunk, all contiguous 1KB.
    // x source is pre-swizzled: LDS[r][slot] = x[r][slot ^ (r&7)] (16B slots).
    const int r7   = lane >> 3;                   // row within this wave's 8-row group
    const int ssrc = (lane & 7) ^ (r7 & 7);       // inverse-swizzled 16B slot
    const float* xsrc = x + (size_t)(row0 + w * 8 + r7) * DIMK + ssrc * 4;

    auto stage = [&](int c, int buf) {
        // B: 16 x 1KB frag blocks / chunk, one per wave
        async_load16(wsB + ((size_t)c * 16 + w) * 512 + lane * 8,
                     Bs + buf * 8192 + w * 512);
        // x: 8 rows x 128B per instr; 16 instrs cover the 128x32f chunk tile
        async_load16(xsrc + c * 32, Xs + buf * 4096 + w * 256);
    };

    stage(0, 0);
    stage(1, 1);
    __syncthreads();

    const int r   = rg * 32 + m;        // this lane's A-frag row (0..127)
    const int rx7 = r & 7;

    for (int c = 0; c < NCH; ++c) {
        const int buf = c & 1;
        const float*    xrow = Xs + buf * 4096 + r * 32;
        const _Float16* bb   = Bs + buf * 8192 + t * 512 + lane * 8;

        // B frags (lane-linear 16B, conflict-free): idx t, t+4, t+8, t+12
        half8v bH0 = *(const half8v*)(bb);
        half8v bL0 = *(const half8v*)(bb + 2048);
        half8v bH1 = *(const half8v*)(bb + 4096);
        half8v bL1 = *(const half8v*)(bb + 6144);

        // x frags: logical slot = kh*4 + h*2 + q, stored at slot ^ (r&7)
        float4 x00 = *(const float4*)(xrow + ((h * 2 + 0) ^ rx7) * 4);
        float4 x01 = *(const float4*)(xrow + ((h * 2 + 1) ^ rx7) * 4);
        float4 x10 = *(const float4*)(xrow + ((4 + h * 2 + 0) ^ rx7) * 4);
        float4 x11 = *(const float4*)(xrow + ((4 + h * 2 + 1) ^ rx7) * 4);

        // convert to split-fp16 planes (in registers, per kh)
        half8v aH0, aL0, aH1, aL1;
        {
            float f[8] = {x00.x, x00.y, x00.z, x00.w, x01.x, x01.y, x01.z, x01.w};
            #pragma unroll
            for (int j = 0; j < 8; ++j) {
                float v = f[j] * 1024.f;
                _Float16 a = (_Float16)v;
                aH0[j] = a; aL0[j] = (_Float16)(v - (float)a);
            }
        }
        {
            float f[8] = {x10.x, x10.y, x10.z, x10.w, x11.x, x11.y, x11.z, x11.w};
            #pragma unroll
            for (int j = 0; j < 8; ++j) {
                float v = f[j] * 1024.f;
                _Float16 a = (_Float16)v;
                aH1[j] = a; aL1[j] = (_Float16)(v - (float)a);
            }
        }

        // 3-pass split MFMA per kh (same op order as R9/R11 refcheck-passed)
        acc = __builtin_amdgcn_mfma_f32_32x32x16_f16(aH0, bH0, acc, 0, 0, 0);
        acc = __builtin_amdgcn_mfma_f32_32x32x16_f16(aH0, bL0, acc, 0, 0, 0);
        acc = __builtin_amdgcn_mfma_f32_32x32x16_f16(aL0, bH0, acc, 0, 0, 0);
        acc = __builtin_amdgcn_mfma_f32_32x32x16_f16(aH1, bH1, acc, 0, 0, 0);
        acc = __builtin_amdgcn_mfma_f32_32x32x16_f16(aH1, bL1, acc, 0, 0, 0);
        acc = __builtin_amdgcn_mfma_f32_32x32x16_f16(aL1, bH1, acc, 0, 0, 0);

        // One barrier/chunk: drains our ds_reads (lgkm) and chunk c+1's DMAs
        // (vmcnt0 -- issued a full chunk ago, so no stall), then it is safe
        // to overwrite buf with chunk c+2.
        __syncthreads();
        if (c + 2 < NCH) stage(c + 2, buf);
    }

    // ---- epilogue ----
    // 32x32 C/D layout: col = lane&31 (expert within tile),
    // row = (reg&3) + 8*(reg>>2) + 4*(lane>>5). Unscale by 2^-26.
    // Write scaled tiles into scratch (reuses staging LDS; last loop barrier
    // guarantees all reads are done), then per-row combine + top2 + scatter.
    const float s = 0x1p-26f;
    constexpr int SLD = 68;                 // 16B-aligned row stride (floats)
    float* scr = (float*)smem;              // [2 plane][128][SLD] = 68 KB
    {
        const int pl   = (t >> 1) * BM * SLD;
        const int colb = (t & 1) * 32 + m;
        #pragma unroll
        for (int reg = 0; reg < 16; ++reg) {
            int rl = (reg & 3) + 8 * (reg >> 2) + 4 * h;     // 0..31
            scr[pl + (rg * 32 + rl) * SLD + colb] = acc[reg] * s;
        }
    }
    __syncthreads();

    {
        int rr = tid >> 3;           // 0..127: row within block
        int s8 = tid & 7;            // 8-expert segment
        const float* gp = scr + rr * SLD + s8 * 8;
        const float* np = scr + BM * SLD + rr * SLD + s8 * 8;
        float4 g0 = *(const float4*)(gp);
        float4 g1 = *(const float4*)(gp + 4);
        float4 n0 = *(const float4*)(np);
        float4 n1 = *(const float4*)(np + 4);
        float4 z0 = *(const float4*)(noise + (size_t)(row0 + rr) * NEXP + s8 * 8);
        float4 z1 = *(const float4*)(noise + (size_t)(row0 + rr) * NEXP + s8 * 8 + 4);
        float gg[8] = {g0.x, g0.y, g0.z, g0.w, g1.x, g1.y, g1.z, g1.w};
        float nn[8] = {n0.x, n0.y, n0.z, n0.w, n1.x, n1.y, n1.z, n1.w};
        float zz[8] = {z0.x, z0.y, z0.z, z0.w, z1.x, z1.y, z1.z, z1.w};
        float v1 = -INFINITY, v2 = -INFINITY;
        int   i1 = 0x7ffffffe,  i2 = 0x7fffffff;
        #pragma unroll
        for (int j = 0; j < 8; ++j) {
            float nv = nn[j];
            float sp = fmaxf(nv, 0.f) + log1pf(expf(-fabsf(nv)));
            float vv = gg[j] + zz[j] * (sp + 0.01f);
            int   e  = s8 * 8 + j;
            if (gt_pair(vv, e, v1, i1)) { v2 = v1; i2 = i1; v1 = vv; i1 = e; }
            else if (gt_pair(vv, e, v2, i2)) { v2 = vv; i2 = e; }
        }
        #pragma unroll
        for (int mm = 1; mm <= 4; mm <<= 1) {    // butterfly over the 8-lane group
            float b1 = __shfl_xor(v1, mm); int ib1 = __shfl_xor(i1, mm);
            float b2 = __shfl_xor(v2, mm); int ib2 = __shfl_xor(i2, mm);
            if (gt_pair(b1, ib1, v1, i1)) {
                float o1 = v1; int oi1 = i1;
                v1 = b1; i1 = ib1;
                if (gt_pair(b2, ib2, o1, oi1)) { v2 = b2; i2 = ib2; }
                else                           { v2 = o1; i2 = oi1; }
            } else if (gt_pair(b1, ib1, v2, i2)) {
                v2 = b1; i2 = ib1;
            }
        }
        // all 8 lanes converge to the row's top2; softmax + scatter directly
        float te = expf(v2 - v1);     // <= 1
        float ga = 1.f / (1.f + te);
        float gb = te * ga;
        float* op = out + (size_t)(row0 + rr) * NEXP + s8 * 8;
        #pragma unroll
        for (int qq = 0; qq < 2; ++qq) {
            int e0 = s8 * 8 + qq * 4;
            float4 o;
            o.x = (e0 + 0 == i1) ? ga : ((e0 + 0 == i2) ? gb : 0.f);
            o.y = (e0 + 1 == i1) ? ga : ((e0 + 1 == i2) ? gb : 0.f);
            o.z = (e0 + 2 == i1) ? ga : ((e0 + 2 == i2) ? gb : 0.f);
            o.w = (e0 + 3 == i1) ? ga : ((e0 + 3 == i2) ? gb : 0.f);
            *(float4*)(op + qq * 4) = o;
        }
    }
}

extern "C" void kernel_launch(void* const* d_in, const int* in_sizes, int n_in,
                              void* d_out, int out_size, void* d_ws, size_t ws_size,
                              hipStream_t stream) {
    const float* x     = (const float*)d_in[0];
    const float* wg    = (const float*)d_in[1];
    const float* wn    = (const float*)d_in[2];
    const float* noise = (const float*)d_in[3];
    float* out = (float*)d_out;
    _Float16* wsB = (_Float16*)d_ws;   // needs 1024 * 1KB = 1 MB

    presplit_kernel<<<dim3(256), 256, 0, stream>>>(wg, wn, wsB);

    const int Brows = in_sizes[0] / DIMK;          // 32768
    dim3 grid(Brows / BM);                         // 256 blocks -> 1/CU, 16 waves/CU
    routing_mfma<<<grid, 1024, 0, stream>>>(x, wsB, noise, out);
}

// Round 10
// 397.993 us; speedup vs baseline: 1.0177x; 1.0177x over previous
//
#include <hip/hip_runtime.h>
#include <math.h>

// RoutingLayer fused via split-fp16 MFMA emulation of fp32 GEMM.
// routing = x@w_gate + noise*(softplus(x@w_noise)+0.01); out = scatter(softmax(top2)).
// x: 32768x2048 fp32, w_*: 2048x64 fp32, noise: 32768x64, out: 32768x64.
//
// R13: fewer, fatter barrier-steps (BK=64). Every prior variant (R4-R12)
// used 64 K-chunks -> 64 barrier-steps and landed at 145-215us regardless
// of pipeline depth, occupancy, barrier removal, or staging-instr count.
// Measured per-step cost ~5600cy vs ~1500cy of work => a fixed per-step
// overhead dominates (cf. m233: 2-phase structural stall doesn't decompose;
// fix in the GEMM ladder was always fatter steps, m93->m97->m201).
// Now each step consumes 64 k: 12 MFMAs + 16 ds_reads + 4 DMA per wave,
// 32 steps. BM=128, 1024 thr = 16 waves (4 rowgroups x 4 coltiles),
// grid 256 = 1 block/CU (16 waves/CU). LDS 128KB: dbuf 32KB B + dbuf 32KB x
// (m201 precedent for 128KB). Sub-chunk order preserved -> bit-identical.
// Everything else verbatim from R12 (refcheck-passed).

typedef _Float16 half8v __attribute__((ext_vector_type(8)));
typedef float f32x16 __attribute__((ext_vector_type(16)));

constexpr int DIMK = 2048;
constexpr int NEXP = 64;
constexpr int BM   = 128;        // rows per block
constexpr int BK   = 64;         // k per barrier-step
constexpr int NST  = DIMK / BK;  // 32 steps

__device__ __forceinline__ void async_load16(const void* g, void* l) {
    // global -> LDS DMA, 16B/lane; LDS dest = uniform base + lane*16,
    // GLOBAL source is per-lane (enables source-side swizzling, m173).
    __builtin_amdgcn_global_load_lds(
        (const __attribute__((address_space(1))) unsigned int*)g,
        (__attribute__((address_space(3))) unsigned int*)l, 16, 0, 0);
}

__device__ __forceinline__ bool gt_pair(float a, int ia, float b, int ib) {
    return (a > b) || (a == b && ia < ib);   // jax top_k: lower index wins ties
}

// ---- pre-kernel: split w' = 65536*[wg|wn] into 2 fp16 planes in 32x32x16
// B-frag order. Frag-block fb = c*16 + kh*8 + p*4 + nt  (1KB each, 1MB total):
// lane holds B[k = c*32 + kh*16 + (lane>>5)*8 + j][n' = nt*32 + (lane&31)]
// where nt 0,1 = w_gate cols 0..63 and nt 2,3 = w_noise cols 0..63.
__global__ __launch_bounds__(256)
void presplit_kernel(const float* __restrict__ wg, const float* __restrict__ wn,
                     _Float16* __restrict__ wsB)
{
    int gid  = blockIdx.x * 256 + threadIdx.x;   // 0..65535 = (fb, lane)
    int lane = gid & 63;
    int fb   = gid >> 6;          // 0..1023
    int nt   = fb & 3;
    int p    = (fb >> 2) & 1;
    int kh   = (fb >> 3) & 1;
    int c    = fb >> 4;
    const float* src = (nt < 2) ? (wg + nt * 32 + (lane & 31))
                                : (wn + (nt - 2) * 32 + (lane & 31));
    int kb = c * 32 + kh * 16 + ((lane >> 5) << 3);
    half8v hp;
    #pragma unroll
    for (int j = 0; j < 8; ++j) {
        float w = src[(size_t)(kb + j) * NEXP] * 65536.0f;
        _Float16 a = (_Float16)w;
        hp[j] = p ? (_Float16)(w - (float)a) : a;
    }
    *(half8v*)(wsB + (size_t)fb * 512 + lane * 8) = hp;
}

// ---- main kernel: 1024 threads = 16 waves as (rg = w>>2, t = w&3).
// Wave tile: 32 rows (rg) x 32 cols of tile t (0=gate-lo,1=gate-hi,2=noise-lo,3=noise-hi).
__global__ __launch_bounds__(1024, 4)
void routing_mfma(const float* __restrict__ x, const _Float16* __restrict__ wsB,
                  const float* __restrict__ noise, float* __restrict__ out)
{
    // 128 KB: [Bs: 2 x 32KB][Xs: 2 x 32KB]; reused as epilogue scratch.
    __shared__ __align__(16) char smem[131072];
    _Float16* Bs = (_Float16*)smem;              // [2][16384] halfs
    float*    Xs = (float*)(smem + 65536);       // [2][8192] floats

    const int tid  = threadIdx.x;
    const int lane = tid & 63;
    const int w    = tid >> 6;          // 0..15
    const int rg   = w >> 2;            // row group (0..3)
    const int t    = w & 3;             // col tile
    const int m    = lane & 31;
    const int h    = lane >> 5;
    const int row0 = blockIdx.x * BM;

    f32x16 acc = {};

    // ---- staging: 4 DMA instrs per wave per step, all contiguous 1KB.
    // x LDS layout [128][64]f; source pre-swizzled in 16B slots:
    // phys slot = logical ^ (row&7)  (XOR touches low 3 of 16 slots only).
    const int lr0 = (w * 2 + 0) * 4 + (lane >> 4);   // local rows for the 2 x-DMAs
    const int lr1 = (w * 2 + 1) * 4 + (lane >> 4);
    const int ss0 = (lane & 15) ^ (lr0 & 7);
    const int ss1 = (lane & 15) ^ (lr1 & 7);
    const float* xsrc0 = x + (size_t)(row0 + lr0) * DIMK + ss0 * 4;
    const float* xsrc1 = x + (size_t)(row0 + lr1) * DIMK + ss1 * 4;

    auto stage = [&](int s, int buf) {
        #pragma unroll
        for (int i = 0; i < 2; ++i) {     // B: 32 x 1KB frag blocks / step
            int j = w + i * 16;
            async_load16(wsB + ((size_t)s * 32 + j) * 512 + lane * 8,
                         Bs + buf * 16384 + j * 512);
        }
        // x: 4 rows x 256B per instr; 32 instrs cover the 128x64f step tile
        async_load16(xsrc0 + s * BK, Xs + buf * 8192 + (w * 2 + 0) * 256);
        async_load16(xsrc1 + s * BK, Xs + buf * 8192 + (w * 2 + 1) * 256);
    };

    stage(0, 0);
    stage(1, 1);
    __syncthreads();

    const int r   = rg * 32 + m;        // this lane's A-frag row (0..127)
    const int rx7 = r & 7;

    for (int s = 0; s < NST; ++s) {
        const int buf = s & 1;
        const float* xrow = Xs + buf * 8192 + r * 64;

        #pragma unroll
        for (int u = 0; u < 2; ++u) {             // two 32-k sub-chunks
            const _Float16* bb = Bs + buf * 16384 + u * 8192 + t * 512 + lane * 8;

            // B frags (lane-linear 16B, conflict-free)
            half8v bH0 = *(const half8v*)(bb);
            half8v bL0 = *(const half8v*)(bb + 2048);
            half8v bH1 = *(const half8v*)(bb + 4096);
            half8v bL1 = *(const half8v*)(bb + 6144);

            // x frags: logical 16B slot = u*8 + kh*4 + h*2 + q, stored ^rx7
            float4 x00 = *(const float4*)(xrow + ((u * 8 + h * 2 + 0) ^ rx7) * 4);
            float4 x01 = *(const float4*)(xrow + ((u * 8 + h * 2 + 1) ^ rx7) * 4);
            float4 x10 = *(const float4*)(xrow + ((u * 8 + 4 + h * 2 + 0) ^ rx7) * 4);
            float4 x11 = *(const float4*)(xrow + ((u * 8 + 4 + h * 2 + 1) ^ rx7) * 4);

            // convert to split-fp16 planes (in registers, per kh)
            half8v aH0, aL0, aH1, aL1;
            {
                float f[8] = {x00.x, x00.y, x00.z, x00.w, x01.x, x01.y, x01.z, x01.w};
                #pragma unroll
                for (int j = 0; j < 8; ++j) {
                    float v = f[j] * 1024.f;
                    _Float16 a = (_Float16)v;
                    aH0[j] = a; aL0[j] = (_Float16)(v - (float)a);
                }
            }
            {
                float f[8] = {x10.x, x10.y, x10.z, x10.w, x11.x, x11.y, x11.z, x11.w};
                #pragma unroll
                for (int j = 0; j < 8; ++j) {
                    float v = f[j] * 1024.f;
                    _Float16 a = (_Float16)v;
                    aH1[j] = a; aL1[j] = (_Float16)(v - (float)a);
                }
            }

            // 3-pass split MFMA per kh (same op order as R9/R11/R12)
            acc = __builtin_amdgcn_mfma_f32_32x32x16_f16(aH0, bH0, acc, 0, 0, 0);
            acc = __builtin_amdgcn_mfma_f32_32x32x16_f16(aH0, bL0, acc, 0, 0, 0);
            acc = __builtin_amdgcn_mfma_f32_32x32x16_f16(aL0, bH0, acc, 0, 0, 0);
            acc = __builtin_amdgcn_mfma_f32_32x32x16_f16(aH1, bH1, acc, 0, 0, 0);
            acc = __builtin_amdgcn_mfma_f32_32x32x16_f16(aH1, bL1, acc, 0, 0, 0);
            acc = __builtin_amdgcn_mfma_f32_32x32x16_f16(aL1, bH1, acc, 0, 0, 0);
        }

        // One barrier/step: drains our ds_reads and step s+1's DMAs (issued
        // a full step ago -> no stall), then buf is safe to overwrite.
        __syncthreads();
        if (s + 2 < NST) stage(s + 2, buf);
    }

    // ---- epilogue (verbatim R12) ----
    // 32x32 C/D layout: col = lane&31 (expert within tile),
    // row = (reg&3) + 8*(reg>>2) + 4*(lane>>5). Unscale by 2^-26.
    const float s = 0x1p-26f;
    constexpr int SLD = 68;                 // 16B-aligned row stride (floats)
    float* scr = (float*)smem;              // [2 plane][128][SLD] = 68 KB
    {
        const int pl   = (t >> 1) * BM * SLD;
        const int colb = (t & 1) * 32 + m;
        #pragma unroll
        for (int reg = 0; reg < 16; ++reg) {
            int rl = (reg & 3) + 8 * (reg >> 2) + 4 * h;     // 0..31
            scr[pl + (rg * 32 + rl) * SLD + colb] = acc[reg] * s;
        }
    }
    __syncthreads();

    {
        int rr = tid >> 3;           // 0..127: row within block
        int s8 = tid & 7;            // 8-expert segment
        const float* gp = scr + rr * SLD + s8 * 8;
        const float* np = scr + BM * SLD + rr * SLD + s8 * 8;
        float4 g0 = *(const float4*)(gp);
        float4 g1 = *(const float4*)(gp + 4);
        float4 n0 = *(const float4*)(np);
        float4 n1 = *(const float4*)(np + 4);
        float4 z0 = *(const float4*)(noise + (size_t)(row0 + rr) * NEXP + s8 * 8);
        float4 z1 = *(const float4*)(noise + (size_t)(row0 + rr) * NEXP + s8 * 8 + 4);
        float gg[8] = {g0.x, g0.y, g0.z, g0.w, g1.x, g1.y, g1.z, g1.w};
        float nn[8] = {n0.x, n0.y, n0.z, n0.w, n1.x, n1.y, n1.z, n1.w};
        float zz[8] = {z0.x, z0.y, z0.z, z0.w, z1.x, z1.y, z1.z, z1.w};
        float v1 = -INFINITY, v2 = -INFINITY;
        int   i1 = 0x7ffffffe,  i2 = 0x7fffffff;
        #pragma unroll
        for (int j = 0; j < 8; ++j) {
            float nv = nn[j];
            float sp = fmaxf(nv, 0.f) + log1pf(expf(-fabsf(nv)));
            float vv = gg[j] + zz[j] * (sp + 0.01f);
            int   e  = s8 * 8 + j;
            if (gt_pair(vv, e, v1, i1)) { v2 = v1; i2 = i1; v1 = vv; i1 = e; }
            else if (gt_pair(vv, e, v2, i2)) { v2 = vv; i2 = e; }
        }
        #pragma unroll
        for (int mm = 1; mm <= 4; mm <<= 1) {    // butterfly over the 8-lane group
            float b1 = __shfl_xor(v1, mm); int ib1 = __shfl_xor(i1, mm);
            float b2 = __shfl_xor(v2, mm); int ib2 = __shfl_xor(i2, mm);
            if (gt_pair(b1, ib1, v1, i1)) {
                float o1 = v1; int oi1 = i1;
                v1 = b1; i1 = ib1;
                if (gt_pair(b2, ib2, o1, oi1)) { v2 = b2; i2 = ib2; }
                else                           { v2 = o1; i2 = oi1; }
            } else if (gt_pair(b1, ib1, v2, i2)) {
                v2 = b1; i2 = ib1;
            }
        }
        // all 8 lanes converge to the row's top2; softmax + scatter directly
        float te = expf(v2 - v1);     // <= 1
        float ga = 1.f / (1.f + te);
        float gb = te * ga;
        float* op = out + (size_t)(row0 + rr) * NEXP + s8 * 8;
        #pragma unroll
        for (int qq = 0; qq < 2; ++qq) {
            int e0 = s8 * 8 + qq * 4;
            float4 o;
            o.x = (e0 + 0 == i1) ? ga : ((e0 + 0 == i2) ? gb : 0.f);
            o.y = (e0 + 1 == i1) ? ga : ((e0 + 1 == i2) ? gb : 0.f);
            o.z = (e0 + 2 == i1) ? ga : ((e0 + 2 == i2) ? gb : 0.f);
            o.w = (e0 + 3 == i1) ? ga : ((e0 + 3 == i2) ? gb : 0.f);
            *(float4*)(op + qq * 4) = o;
        }
    }
}

extern "C" void kernel_launch(void* const* d_in, const int* in_sizes, int n_in,
                              void* d_out, int out_size, void* d_ws, size_t ws_size,
                              hipStream_t stream) {
    const float* x     = (const float*)d_in[0];
    const float* wg    = (const float*)d_in[1];
    const float* wn    = (const float*)d_in[2];
    const float* noise = (const float*)d_in[3];
    float* out = (float*)d_out;
    _Float16* wsB = (_Float16*)d_ws;   // needs 1024 * 1KB = 1 MB

    presplit_kernel<<<dim3(256), 256, 0, stream>>>(wg, wn, wsB);

    const int Brows = in_sizes[0] / DIMK;          // 32768
    dim3 grid(Brows / BM);                         // 256 blocks -> 1/CU, 16 waves/CU
    routing_mfma<<<grid, 1024, 0, stream>>>(x, wsB, noise, out);
}